// Round 5
// baseline (157.648 us; speedup 1.0000x reference)
//
#include <hip/hip_runtime.h>

#define HH 2048
#define WW 2048
#define NN (HH*WW)

static constexpr unsigned RANK0 = 1677721u;   // floor(0.4*(NN-1))
static constexpr unsigned KEYLO = 0xB000u;
static constexpr unsigned KEYHI_ = 0xC000u;
static constexpr int NBINS = 4096;
static constexpr int NPART = 2048;

// 3-stage fused morph tile geometry: 32x128 tile, halo 3 (+1 ring)
#define TH 32
#define TW 128
#define LRR 38           // 32 + 2*3 rows
#define GG 34            // col float4-groups: 136 data cols (c0-4 .. c0+131)
#define LCP 140          // padded LDS row stride (136 data + 4 pad; 140%32=12)

struct Scal {
  unsigned keyhiA, keyhiB, rA, rB;      // coarse result: hi16 bins + ranks within
  unsigned midA_, midB_, rA2, rB2;      // mid-byte bins + ranks within
  double thr, c0, c1;
};

// ws layout: [bufA NN floats][zeroed ctl: coarse 16KB|under|over|midA|midB|lowA|lowB][scal][part]
static constexpr size_t OFF_CTL    = (size_t)NN * 4;
static constexpr size_t OFF_COARSE = OFF_CTL;
static constexpr size_t OFF_UNDER  = OFF_CTL + (size_t)NBINS * 4;
static constexpr size_t OFF_OVER   = OFF_UNDER + 4;
static constexpr size_t OFF_MIDA   = OFF_OVER + 4;
static constexpr size_t OFF_MIDB   = OFF_MIDA + 1024;
static constexpr size_t OFF_LOWA   = OFF_MIDB + 1024;
static constexpr size_t OFF_LOWB   = OFF_LOWA + 1024;
static constexpr size_t CTL_END    = OFF_LOWB + 1024;
static constexpr size_t CTL_BYTES  = CTL_END - OFF_CTL;      // 20488
static constexpr size_t OFF_SCAL   = CTL_END;                // 8-aligned
static constexpr size_t OFF_PART   = OFF_SCAL + 64;

__device__ __forceinline__ float mx3(float a, float b, float c){ return fmaxf(fmaxf(a,b),c); }
__device__ __forceinline__ float mn3(float a, float b, float c){ return fminf(fminf(a,b),c); }

__device__ __forceinline__ unsigned keyf(float x){
  unsigned b = __float_as_uint(x);
  return (b & 0x80000000u) ? ~b : (b | 0x80000000u);
}
__device__ __forceinline__ float keyinv(unsigned k){
  unsigned b = (k & 0x80000000u) ? (k ^ 0x80000000u) : ~k;
  return __uint_as_float(b);
}

// 6-float window from one LDS row: aligned b128 + two independent b32 reads.
__device__ __forceinline__ void loadwin(const float* __restrict__ src, int rowbase,
                                        int colL, int colC, int colR, float w[6]){
  float4 v = *reinterpret_cast<const float4*>(&src[rowbase + colC]);
  w[0] = src[rowbase + colL];
  w[1] = v.x; w[2] = v.y; w[3] = v.z; w[4] = v.w;
  w[5] = src[rowbase + colR];
}

__device__ __forceinline__ void morph4(bool DIL,
    const float pr[6], const float cr[6], const float nr[6], float w[4]){
  #pragma unroll
  for (int i = 0; i < 4; i++){
    if (DIL){
      float Ah = mx3(cr[i],   cr[i+1], cr[i+2]);
      float Av = mx3(pr[i+1], cr[i+1], nr[i+1]);
      float Ad = mx3(pr[i],   cr[i+1], nr[i+2]);
      float Aa = mx3(pr[i+2], cr[i+1], nr[i]);
      float tm = mx3(pr[i], pr[i+1], pr[i+2]);
      float bm = mx3(nr[i], nr[i+1], nr[i+2]);
      float M9 = mx3(tm, Ah, bm);
      w[i] = fmaxf(M9, 1.0f + fminf(fminf(Ah,Av), fminf(Ad,Aa)));
    } else {
      float Bh = mn3(cr[i],   cr[i+1], cr[i+2]);
      float Bv = mn3(pr[i+1], cr[i+1], nr[i+1]);
      float Bd = mn3(pr[i],   cr[i+1], nr[i+2]);
      float Ba = mn3(pr[i+2], cr[i+1], nr[i]);
      float tm = mn3(pr[i], pr[i+1], pr[i+2]);
      float bm = mn3(nr[i], nr[i+1], nr[i+2]);
      float m9 = mn3(tm, Bh, bm);
      w[i] = fminf(m9, fmaxf(fmaxf(Bh,Bv), fmaxf(Bd,Ba)) - 1.0f);
    }
  }
}

// 3 smoothing ops in LDS (PASS 0: D,E,E ; PASS 1: D,D,E). Last stage stores to
// global directly from registers; PASS 1 also builds the coarse histogram.
template<int PASS>
__global__ __launch_bounds__(256)
void morph3_k(const float* __restrict__ in, float* __restrict__ outp,
              unsigned* __restrict__ gh, unsigned* __restrict__ under,
              unsigned* __restrict__ over){
  __shared__ float lds[LRR*LCP];
  __shared__ unsigned lh[PASS ? NBINS/2 : 1];   // packed u16 bins
  const int tilec = blockIdx.x & 15;
  const int tiler = blockIdx.x >> 4;
  const int r0 = tiler*TH, c0 = tilec*TW;

  if (PASS) for (int i = threadIdx.x; i < NBINS/2; i += 256) lh[i] = 0;

  // load LRR x GG float4 (rows r0-3..r0+34, cols c0-4..c0+131), zero-padded
  for (int idx = threadIdx.x; idx < LRR*GG; idx += 256){
    int lr = idx / GG, g = idx % GG;
    int gr = r0 - 3 + lr, gc = c0 - 4 + 4*g;
    float4 v = make_float4(0.f,0.f,0.f,0.f);
    if ((unsigned)gr < (unsigned)HH && (unsigned)gc < (unsigned)WW)
      v = *reinterpret_cast<const float4*>(in + (size_t)gr*WW + gc);
    *reinterpret_cast<float4*>(&lds[lr*LCP + 4*g]) = v;
  }
  __syncthreads();

  const int t = threadIdx.x;
  const int g = t % GG, s = t / GG;      // 6 active strips of 6 rows
  const bool active = (s < 6);
  const int rbase = 1 + 6*s;             // strip computes local rows rbase..rbase+5
  const int colC = 4*g;
  const int colL = g ? 4*g - 1 : 0;                 // clamp: garbage -> halo only
  const int colR = (g == GG-1) ? 4*GG - 1 : 4*g + 4;
  const int gcBase = c0 - 4 + 4*g;

  float o0[4],o1[4],o2[4],o3[4],o4[4],o5[4];

  #pragma unroll 1
  for (int st = 0; st < 3; st++){
    const bool DIL = (st == 0) ? true : (st == 1 ? (PASS != 0) : false);
    if (active){
      float p[6], c[6], n[6];
      loadwin(lds, (rbase-1)*LCP, colL, colC, colR, p);
      loadwin(lds, (rbase  )*LCP, colL, colC, colR, c);
      #pragma unroll
      for (int k = 0; k < 6; k++){
        float* w = (k==0)?o0:(k==1)?o1:(k==2)?o2:(k==3)?o3:(k==4)?o4:o5;
        loadwin(lds, (rbase+1+k)*LCP, colL, colC, colR, n);
        morph4(DIL, p, c, n, w);
        int gr = r0 - 3 + rbase + k;     // zero-pad enforcement each stage
        if ((unsigned)gr >= (unsigned)HH){
          w[0]=w[1]=w[2]=w[3]=0.f;
        } else {
          #pragma unroll
          for (int i = 0; i < 4; i++)
            if ((unsigned)(gcBase + i) >= (unsigned)WW) w[i] = 0.f;
        }
        #pragma unroll
        for (int i = 0; i < 6; i++){ p[i]=c[i]; c[i]=n[i]; }
      }
    }
    if (st < 2){
      __syncthreads();
      if (active){
        *reinterpret_cast<float4*>(&lds[(rbase+0)*LCP+colC]) = make_float4(o0[0],o0[1],o0[2],o0[3]);
        *reinterpret_cast<float4*>(&lds[(rbase+1)*LCP+colC]) = make_float4(o1[0],o1[1],o1[2],o1[3]);
        *reinterpret_cast<float4*>(&lds[(rbase+2)*LCP+colC]) = make_float4(o2[0],o2[1],o2[2],o2[3]);
        *reinterpret_cast<float4*>(&lds[(rbase+3)*LCP+colC]) = make_float4(o3[0],o3[1],o3[2],o3[3]);
        *reinterpret_cast<float4*>(&lds[(rbase+4)*LCP+colC]) = make_float4(o4[0],o4[1],o4[2],o4[3]);
        *reinterpret_cast<float4*>(&lds[(rbase+5)*LCP+colC]) = make_float4(o5[0],o5[1],o5[2],o5[3]);
      }
      __syncthreads();
    }
  }

  // epilogue: pristine center = local rows [3,35), groups [1,33): store from regs
  unsigned uc = 0, oc = 0;
  if (active && g >= 1 && g <= 32){
    #pragma unroll
    for (int k = 0; k < 6; k++){
      const float* w = (k==0)?o0:(k==1)?o1:(k==2)?o2:(k==3)?o3:(k==4)?o4:o5;
      int row = rbase + k;
      if (row >= 3 && row < 35){
        int gr = r0 + row - 3;
        *reinterpret_cast<float4*>(outp + (size_t)gr*WW + gcBase) =
            make_float4(w[0],w[1],w[2],w[3]);
        if (PASS){
          #pragma unroll
          for (int i = 0; i < 4; i++){
            unsigned key = keyf(w[i]);
            unsigned hi = key >> 16;
            if (hi >= KEYLO && hi < KEYHI_){
              unsigned bin = hi - KEYLO;
              atomicAdd(&lh[bin >> 1], 1u << ((bin & 1) << 4));
            }
            else if (hi < KEYLO) uc++;
            else                 oc++;
          }
        }
      }
    }
  }
  if (PASS){
    __syncthreads();
    for (int i = threadIdx.x; i < NBINS/2; i += 256){
      unsigned w = lh[i];
      if (w & 0xFFFFu) atomicAdd(&gh[2*i],   w & 0xFFFFu);
      if (w >> 16)     atomicAdd(&gh[2*i+1], w >> 16);
    }
    if (uc) atomicAdd(under, uc);
    if (oc) atomicAdd(over, oc);
  }
}

__global__ void scan_coarse_k(const unsigned* __restrict__ gh, const unsigned* __restrict__ under,
                              Scal* __restrict__ sc){
  __shared__ unsigned part[256];
  __shared__ unsigned excl[256];
  int t = threadIdx.x;
  unsigned loc = 0;
  #pragma unroll
  for (int i = 0; i < NBINS/256; i++) loc += gh[t*(NBINS/256) + i];
  part[t] = loc;
  __syncthreads();
  if (t == 0){
    unsigned run = under[0];
    for (int i = 0; i < 256; i++){ excl[i] = run; run += part[i]; }
  }
  __syncthreads();
  unsigned run = excl[t];
  const unsigned r0 = RANK0, r1 = RANK0 + 1;
  #pragma unroll
  for (int i = 0; i < NBINS/256; i++){
    unsigned idx = t*(NBINS/256) + i;
    unsigned cc = gh[idx];
    if (cc){
      if (r0 >= run && r0 - run < cc){ sc->keyhiA = KEYLO + idx; sc->rA = r0 - run; }
      if (r1 >= run && r1 - run < cc){ sc->keyhiB = KEYLO + idx; sc->rB = r1 - run; }
    }
    run += cc;
  }
}

// mid-byte histogram (bits 15..8) of keys whose hi16 matches keyhiA / keyhiB
__global__ __launch_bounds__(256)
void fine_mid_k(const float* __restrict__ x, const Scal* __restrict__ sc,
                unsigned* __restrict__ midA, unsigned* __restrict__ midB){
  __shared__ unsigned hA[256], hB[256];
  hA[threadIdx.x] = 0; hB[threadIdx.x] = 0;
  __syncthreads();
  unsigned ha = sc->keyhiA, hb = sc->keyhiB;
  bool dup = (ha == hb);
  const int nItems = NN/4;
  for (int it = blockIdx.x*blockDim.x + threadIdx.x; it < nItems; it += gridDim.x*blockDim.x){
    float4 v = reinterpret_cast<const float4*>(x)[it];
    float vv[4] = {v.x, v.y, v.z, v.w};
    #pragma unroll
    for (int t = 0; t < 4; t++){
      unsigned key = keyf(vv[t]);
      unsigned hi = key >> 16;
      if (hi == ha)      atomicAdd(&hA[(key >> 8) & 0xFFu], 1u);
      else if (hi == hb) atomicAdd(&hB[(key >> 8) & 0xFFu], 1u);
    }
  }
  __syncthreads();
  unsigned ca = hA[threadIdx.x];
  if (ca) atomicAdd(&midA[threadIdx.x], ca);
  if (!dup){
    unsigned cb = hB[threadIdx.x];
    if (cb) atomicAdd(&midB[threadIdx.x], cb);
  }
}

__global__ void scan_mid_k(const unsigned* __restrict__ midA, const unsigned* __restrict__ midB,
                           Scal* __restrict__ sc){
  __shared__ unsigned h[256], excl[256];
  int t = threadIdx.x;
  bool dup = (sc->keyhiA == sc->keyhiB);
  unsigned rA = sc->rA, rB = sc->rB;
  h[t] = midA[t];
  __syncthreads();
  if (t == 0){ unsigned run = 0; for (int i = 0; i < 256; i++){ excl[i] = run; run += h[i]; } }
  __syncthreads();
  if (rA >= excl[t] && rA - excl[t] < h[t]){ sc->midA_ = (unsigned)t; sc->rA2 = rA - excl[t]; }
  if (dup && rB >= excl[t] && rB - excl[t] < h[t]){ sc->midB_ = (unsigned)t; sc->rB2 = rB - excl[t]; }
  if (!dup){
    __syncthreads();
    h[t] = midB[t];
    __syncthreads();
    if (t == 0){ unsigned run = 0; for (int i = 0; i < 256; i++){ excl[i] = run; run += h[i]; } }
    __syncthreads();
    if (rB >= excl[t] && rB - excl[t] < h[t]){ sc->midB_ = (unsigned)t; sc->rB2 = rB - excl[t]; }
  }
}

// low-byte histogram of keys with hi16 AND mid byte matching
__global__ __launch_bounds__(256)
void fine_low_k(const float* __restrict__ x, const Scal* __restrict__ sc,
                unsigned* __restrict__ lowA, unsigned* __restrict__ lowB){
  __shared__ unsigned hA[256], hB[256];
  hA[threadIdx.x] = 0; hB[threadIdx.x] = 0;
  __syncthreads();
  unsigned ha = sc->keyhiA, hb = sc->keyhiB;
  unsigned ma = sc->midA_, mb = sc->midB_;
  bool dup = (ha == hb) && (ma == mb);
  const int nItems = NN/4;
  for (int it = blockIdx.x*blockDim.x + threadIdx.x; it < nItems; it += gridDim.x*blockDim.x){
    float4 v = reinterpret_cast<const float4*>(x)[it];
    float vv[4] = {v.x, v.y, v.z, v.w};
    #pragma unroll
    for (int t = 0; t < 4; t++){
      unsigned key = keyf(vv[t]);
      unsigned hi = key >> 16;
      unsigned m  = (key >> 8) & 0xFFu;
      if (hi == ha && m == ma)      atomicAdd(&hA[key & 0xFFu], 1u);
      else if (hi == hb && m == mb) atomicAdd(&hB[key & 0xFFu], 1u);
    }
  }
  __syncthreads();
  unsigned ca = hA[threadIdx.x];
  if (ca) atomicAdd(&lowA[threadIdx.x], ca);
  if (!dup){
    unsigned cb = hB[threadIdx.x];
    if (cb) atomicAdd(&lowB[threadIdx.x], cb);
  }
}

__global__ void scan_low_k(const unsigned* __restrict__ lowA, const unsigned* __restrict__ lowB,
                           Scal* __restrict__ sc){
  __shared__ unsigned h[256], excl[256];
  __shared__ unsigned kfound[2];
  int t = threadIdx.x;
  bool dup = (sc->keyhiA == sc->keyhiB) && (sc->midA_ == sc->midB_);
  unsigned rA2 = sc->rA2, rB2 = sc->rB2;
  h[t] = lowA[t];
  __syncthreads();
  if (t == 0){ unsigned run = 0; for (int i = 0; i < 256; i++){ excl[i] = run; run += h[i]; } }
  __syncthreads();
  if (rA2 >= excl[t] && rA2 - excl[t] < h[t]) kfound[0] = (unsigned)t;
  if (dup && rB2 >= excl[t] && rB2 - excl[t] < h[t]) kfound[1] = (unsigned)t;
  if (!dup){
    __syncthreads();
    h[t] = lowB[t];
    __syncthreads();
    if (t == 0){ unsigned run = 0; for (int i = 0; i < 256; i++){ excl[i] = run; run += h[i]; } }
    __syncthreads();
    if (rB2 >= excl[t] && rB2 - excl[t] < h[t]) kfound[1] = (unsigned)t;
  }
  __syncthreads();
  if (t == 0){
    unsigned ka = (sc->keyhiA << 16) | (sc->midA_ << 8) | kfound[0];
    unsigned kb = (sc->keyhiB << 16) | (sc->midB_ << 8) | kfound[1];
    double va = (double)keyinv(ka), vb = (double)keyinv(kb);
    const double FRAC = 0.4*(double)(NN-1) - (double)RANK0;   // np's interpolation gamma
    sc->thr = va + (vb - va) * FRAC;
  }
}

// load cols q-1..q+4 of `row` with zero padding (rows and cols)
__device__ __forceinline__ void load6(const float* __restrict__ p, int row, int q, float r[6]){
  if (row < 0 || row >= HH){
    r[0]=r[1]=r[2]=r[3]=r[4]=r[5]=0.f;
    return;
  }
  const float* rp = p + (size_t)row * WW;
  float4 cc = *reinterpret_cast<const float4*>(rp + q);
  r[0] = (q > 0) ? rp[q-1] : 0.f;
  r[1]=cc.x; r[2]=cc.y; r[3]=cc.z; r[4]=cc.w;
  r[5] = (q+4 < WW) ? rp[q+4] : 0.f;
}

// balloon step: aux = 1 + M9(x) inline; xb = (origin > thr) ? aux : x.
// f64 partial sums of origin, xb, origin*xb per block.
__global__ __launch_bounds__(256)
void balloon_k(const float* __restrict__ x, const float* __restrict__ orig,
               float* __restrict__ xb, const Scal* __restrict__ sc, double* __restrict__ part){
  double thr = sc->thr;
  double s0 = 0.0, s1 = 0.0, s2 = 0.0;   // So, Sx, Sox
  const int nItems = NN/4;
  for (int it = blockIdx.x*blockDim.x + threadIdx.x; it < nItems; it += gridDim.x*blockDim.x){
    int i = it >> 9;
    int q = (it & 511) << 2;
    float a[6], b[6], c[6];
    load6(x, i-1, q, a);
    load6(x, i,   q, b);
    load6(x, i+1, q, c);
    float4 og = *reinterpret_cast<const float4*>(orig + (size_t)i*WW + q);
    float ov[4] = {og.x, og.y, og.z, og.w};
    float r[4];
    #pragma unroll
    for (int t = 0; t < 4; t++){
      float M9 = mx3(mx3(a[t],a[t+1],a[t+2]), mx3(b[t],b[t+1],b[t+2]), mx3(c[t],c[t+1],c[t+2]));
      float aux = 1.0f + M9;
      float nx = ((double)ov[t] > thr) ? aux : b[t+1];
      r[t] = nx;
      s0 += (double)ov[t];
      s1 += (double)nx;
      s2 += (double)ov[t] * (double)nx;
    }
    *reinterpret_cast<float4*>(xb + (size_t)i*WW + q) = make_float4(r[0],r[1],r[2],r[3]);
  }
  for (int off = 32; off > 0; off >>= 1){
    s0 += __shfl_down(s0, off);
    s1 += __shfl_down(s1, off);
    s2 += __shfl_down(s2, off);
  }
  __shared__ double red[4][3];
  int lane = threadIdx.x & 63, wv = threadIdx.x >> 6;
  if (lane == 0){ red[wv][0] = s0; red[wv][1] = s1; red[wv][2] = s2; }
  __syncthreads();
  if (threadIdx.x == 0){
    part[blockIdx.x*3+0] = red[0][0]+red[1][0]+red[2][0]+red[3][0];
    part[blockIdx.x*3+1] = red[0][1]+red[1][1]+red[2][1]+red[3][1];
    part[blockIdx.x*3+2] = red[0][2]+red[1][2]+red[2][2]+red[3][2];
  }
}

__global__ void c0c1_k(const double* __restrict__ part, Scal* __restrict__ sc){
  int t = threadIdx.x;
  double s0 = 0, s1 = 0, s2 = 0;
  for (int b = t; b < NPART; b += 256){
    s0 += part[b*3+0]; s1 += part[b*3+1]; s2 += part[b*3+2];
  }
  for (int off = 32; off > 0; off >>= 1){
    s0 += __shfl_down(s0, off);
    s1 += __shfl_down(s1, off);
    s2 += __shfl_down(s2, off);
  }
  __shared__ double red[4][3];
  int lane = t & 63, wv = t >> 6;
  if (lane == 0){ red[wv][0] = s0; red[wv][1] = s1; red[wv][2] = s2; }
  __syncthreads();
  if (t == 0){
    double So = red[0][0]+red[1][0]+red[2][0]+red[3][0];
    double Sx = red[0][1]+red[1][1]+red[2][1]+red[3][1];
    double Sox= red[0][2]+red[1][2]+red[2][2]+red[3][2];
    sc->c0 = (So - Sox) / ((double)NN - Sx + 1e-8);
    sc->c1 = Sox / (Sx + 1e-8);
  }
}

__global__ __launch_bounds__(256)
void final_k(const float* __restrict__ orig, const float* __restrict__ xb,
             const Scal* __restrict__ sc, float* __restrict__ out){
  double c0 = sc->c0, c1 = sc->c1;
  const int nItems = NN/4;
  for (int it = blockIdx.x*blockDim.x + threadIdx.x; it < nItems; it += gridDim.x*blockDim.x){
    float4 og = reinterpret_cast<const float4*>(orig)[it];
    float4 xv = reinterpret_cast<const float4*>(xb)[it];
    float ov[4] = {og.x, og.y, og.z, og.w};
    float xx[4] = {xv.x, xv.y, xv.z, xv.w};
    float r[4];
    #pragma unroll
    for (int t = 0; t < 4; t++){
      double o = (double)ov[t];
      double d1 = o - c1, d0 = o - c0;
      double cv = d1*d1 - d0*d0;
      r[t] = (cv < 0.0) ? 1.0f : ((cv > 0.0) ? 0.0f : xx[t]);
    }
    reinterpret_cast<float4*>(out)[it] = make_float4(r[0],r[1],r[2],r[3]);
  }
}

extern "C" void kernel_launch(void* const* d_in, const int* in_sizes, int n_in,
                              void* d_out, int out_size, void* d_ws, size_t ws_size,
                              hipStream_t stream) {
  const float* input  = (const float*)d_in[0];
  const float* origin = (const float*)d_in[1];
  float* out = (float*)d_out;

  char* ws = (char*)d_ws;
  float*    bufA   = (float*)ws;
  unsigned* coarse = (unsigned*)(ws + OFF_COARSE);
  unsigned* under  = (unsigned*)(ws + OFF_UNDER);
  unsigned* over   = (unsigned*)(ws + OFF_OVER);
  unsigned* midA   = (unsigned*)(ws + OFF_MIDA);
  unsigned* midB   = (unsigned*)(ws + OFF_MIDB);
  unsigned* lowA   = (unsigned*)(ws + OFF_LOWA);
  unsigned* lowB   = (unsigned*)(ws + OFF_LOWB);
  Scal*     scal   = (Scal*)(ws + OFF_SCAL);
  double*   part   = (double*)(ws + OFF_PART);

  hipMemsetAsync(ws + OFF_CTL, 0, CTL_BYTES, stream);

  // smoothing D,E,E,D,D,E split into two 3-stage kernels; coarse hist fused in pass 2
  morph3_k<0><<<(HH/TH)*(WW/TW), 256, 0, stream>>>(input, bufA, nullptr, nullptr, nullptr);
  morph3_k<1><<<(HH/TH)*(WW/TW), 256, 0, stream>>>(bufA, out, coarse, under, over);

  scan_coarse_k<<<1, 256, 0, stream>>>(coarse, under, scal);
  fine_mid_k<<<2048, 256, 0, stream>>>(out, scal, midA, midB);
  scan_mid_k<<<1, 256, 0, stream>>>(midA, midB, scal);
  fine_low_k<<<2048, 256, 0, stream>>>(out, scal, lowA, lowB);
  scan_low_k<<<1, 256, 0, stream>>>(lowA, lowB, scal);

  balloon_k<<<NPART, 256, 0, stream>>>(out, origin, bufA, scal, part);   // xb in bufA
  c0c1_k<<<1, 256, 0, stream>>>(part, scal);
  final_k<<<2048, 256, 0, stream>>>(origin, bufA, scal, out);
}

// Round 6
// 143.633 us; speedup vs baseline: 1.0976x; 1.0976x over previous
//
#include <hip/hip_runtime.h>

#define HH 2048
#define WW 2048
#define NN (HH*WW)

static constexpr unsigned RANK0 = 1677721u;   // floor(0.4*(NN-1))
static constexpr unsigned KEYLO = 0xB000u;
static constexpr unsigned KEYHI_ = 0xC000u;
static constexpr int NBINS = 4096;
static constexpr int NPART = 2048;
static constexpr int MORPH_BLOCKS = 512;      // 2 tiles per block, 1024 tiles

// fused morph tile geometry (round-3 proven): 32x128 tile, halo 6
#define TH 32
#define TW 128
#define LR 44            // TH + 12 rows
#define LCP 148          // padded LDS row stride in floats (data cols [0,144))

struct Scal {
  unsigned keyhiA, keyhiB, rA, rB;      // coarse result: hi16 bins + ranks within
  unsigned midA_, midB_, rA2, rB2;      // mid-byte bins + ranks within
  double thr, c0, c1;
};

// ws layout: [bufA NN floats][zeroed ctl][scal][part]
static constexpr size_t OFF_CTL    = (size_t)NN * 4;
static constexpr size_t OFF_COARSE = OFF_CTL;
static constexpr size_t OFF_UNDER  = OFF_CTL + (size_t)NBINS * 4;
static constexpr size_t OFF_OVER   = OFF_UNDER + 4;
static constexpr size_t OFF_MIDA   = OFF_OVER + 4;
static constexpr size_t OFF_MIDB   = OFF_MIDA + 1024;
static constexpr size_t OFF_LOWA   = OFF_MIDB + 1024;
static constexpr size_t OFF_LOWB   = OFF_LOWA + 1024;
static constexpr size_t CTL_END    = OFF_LOWB + 1024;
static constexpr size_t CTL_BYTES  = CTL_END - OFF_CTL;
static constexpr size_t OFF_SCAL   = CTL_END;                // 8-aligned
static constexpr size_t OFF_PART   = OFF_SCAL + 64;

__device__ __forceinline__ float mx3(float a, float b, float c){ return fmaxf(fmaxf(a,b),c); }
__device__ __forceinline__ float mn3(float a, float b, float c){ return fminf(fminf(a,b),c); }

__device__ __forceinline__ unsigned keyf(float x){
  unsigned b = __float_as_uint(x);
  return (b & 0x80000000u) ? ~b : (b | 0x80000000u);
}
__device__ __forceinline__ float keyinv(unsigned k){
  unsigned b = (k & 0x80000000u) ? (k ^ 0x80000000u) : ~k;
  return __uint_as_float(b);
}

// read one LDS row window for col-group g: aligned float4 + neighbors via shuffle;
// wave-boundary / tile-edge lanes patch with a clamped LDS read (clamp garbage
// only touches cols 0/143 which stay outside the pristine ring at every stage).
__device__ __forceinline__ void loadrow(const float* __restrict__ src, int lr, int g, int lane,
                                        float4& v, float& L, float& R){
  v = *reinterpret_cast<const float4*>(&src[lr*LCP + 4*g]);
  L = __shfl_up(v.w, 1);
  R = __shfl_down(v.x, 1);
  if (lane == 0 || g == 0)   L = src[lr*LCP + (g ? 4*g - 1 : 0)];
  if (lane == 63 || g == 35) R = src[lr*LCP + ((g == 35) ? 143 : 4*g + 4)];
}

__device__ __forceinline__ void morph4(bool DIL,
    const float pr[6], const float cr[6], const float nr[6], float w[4]){
  #pragma unroll
  for (int i = 0; i < 4; i++){
    if (DIL){
      float Ah = mx3(cr[i],   cr[i+1], cr[i+2]);
      float Av = mx3(pr[i+1], cr[i+1], nr[i+1]);
      float Ad = mx3(pr[i],   cr[i+1], nr[i+2]);
      float Aa = mx3(pr[i+2], cr[i+1], nr[i]);
      float tm = mx3(pr[i], pr[i+1], pr[i+2]);
      float bm = mx3(nr[i], nr[i+1], nr[i+2]);
      float M9 = mx3(tm, Ah, bm);
      w[i] = fmaxf(M9, 1.0f + fminf(fminf(Ah,Av), fminf(Ad,Aa)));
    } else {
      float Bh = mn3(cr[i],   cr[i+1], cr[i+2]);
      float Bv = mn3(pr[i+1], cr[i+1], nr[i+1]);
      float Bd = mn3(pr[i],   cr[i+1], nr[i+2]);
      float Ba = mn3(pr[i+2], cr[i+1], nr[i]);
      float tm = mn3(pr[i], pr[i+1], pr[i+2]);
      float bm = mn3(nr[i], nr[i+1], nr[i+2]);
      float m9 = mn3(tm, Bh, bm);
      w[i] = fminf(m9, fmaxf(fmaxf(Bh,Bv), fmaxf(Bd,Ba)) - 1.0f);
    }
  }
}

// All 6 smoothing ops (D,E,E,D,D,E) per 32x128 tile in double-buffered LDS.
// Each block handles 2 tiles; tile1's global loads are issued into registers
// BEFORE tile0's compute so HBM latency hides under the LDS phases.
__global__ __launch_bounds__(256)
void fused_morph_k(const float* __restrict__ in, float* __restrict__ out,
                   unsigned* __restrict__ gh, unsigned* __restrict__ under,
                   unsigned* __restrict__ over){
  __shared__ float lds[2][LR*LCP];
  __shared__ unsigned lh[NBINS/2];       // packed u16 bins; <=8192 per bin over 2 tiles
  for (int i = threadIdx.x; i < NBINS/2; i += 256) lh[i] = 0;

  const int t = threadIdx.x;
  const int g = t % 36, s = t / 36;      // strip s computes rows [6s+1, 6s+7)
  const bool active = (t < 252);
  const int lane = t & 63;
  const bool dilf[6] = {true,false,false,true,true,false};

  int tile = blockIdx.x;
  // ---- stage-in tile0: 44 rows x 36 float4 (rows r0-6.., cols c0-8..), zero-padded
  {
    const int r0 = (tile >> 4)*TH, c0 = (tile & 15)*TW;
    for (int idx = t; idx < LR*36; idx += 256){
      int lr = idx / 36, gq = idx % 36;
      int gr = r0 - 6 + lr, gc = c0 - 8 + 4*gq;
      float4 v = make_float4(0.f,0.f,0.f,0.f);
      if ((unsigned)gr < (unsigned)HH && (unsigned)gc < (unsigned)WW)
        v = *reinterpret_cast<const float4*>(in + (size_t)gr*WW + gc);
      *reinterpret_cast<float4*>(&lds[0][lr*LCP + 4*gq]) = v;
    }
  }
  __syncthreads();

  unsigned uc = 0, oc = 0;
  float4 pref[7];

  #pragma unroll 1
  for (int tt = 0; tt < 2; tt++){
    const int r0 = (tile >> 4)*TH, c0 = (tile & 15)*TW;
    // issue next tile's loads now; consumed after this tile's compute
    if (tt == 0){
      const int tile1 = blockIdx.x + MORPH_BLOCKS;
      const int r1 = (tile1 >> 4)*TH, c1 = (tile1 & 15)*TW;
      #pragma unroll
      for (int j = 0; j < 7; j++){
        int idx = t + j*256;
        float4 v = make_float4(0.f,0.f,0.f,0.f);
        if (idx < LR*36){
          int lr = idx / 36, gq = idx % 36;
          int gr = r1 - 6 + lr, gc = c1 - 8 + 4*gq;
          if ((unsigned)gr < (unsigned)HH && (unsigned)gc < (unsigned)WW)
            v = *reinterpret_cast<const float4*>(in + (size_t)gr*WW + gc);
        }
        pref[j] = v;
      }
    }
    const int gcBase = c0 - 8 + 4*g;

    #pragma unroll 1
    for (int st = 0; st < 6; st++){
      const float* src = lds[st & 1];
      float*       dst = lds[(st & 1) ^ 1];
      if (active){
        const bool DIL = dilf[st];
        float4 vp, vc;  float pL,pR,cL,cR;
        loadrow(src, 6*s,     g, lane, vp, pL, pR);
        loadrow(src, 6*s + 1, g, lane, vc, cL, cR);
        #pragma unroll 1
        for (int k = 0; k < 6; k++){
          int lr = 6*s + 1 + k;
          float4 vn; float nL,nR;
          loadrow(src, lr + 1, g, lane, vn, nL, nR);
          float pr[6] = {pL, vp.x, vp.y, vp.z, vp.w, pR};
          float cr[6] = {cL, vc.x, vc.y, vc.z, vc.w, cR};
          float nr[6] = {nL, vn.x, vn.y, vn.z, vn.w, nR};
          float w[4];
          morph4(DIL, pr, cr, nr, w);
          int gr = r0 - 6 + lr;
          if ((unsigned)gr >= (unsigned)HH){
            w[0]=w[1]=w[2]=w[3]=0.f;
          } else {
            #pragma unroll
            for (int i = 0; i < 4; i++)
              if ((unsigned)(gcBase + i) >= (unsigned)WW) w[i] = 0.f;
          }
          *reinterpret_cast<float4*>(&dst[lr*LCP + 4*g]) = make_float4(w[0],w[1],w[2],w[3]);
          vp = vc; pL = cL; pR = cR;
          vc = vn; cL = nL; cR = nR;
        }
      }
      __syncthreads();
    }

    // epilogue: store + hist of the pristine 32x128 center (final values in lds[0])
    #pragma unroll
    for (int ii = 0; ii < 4; ii++){
      int idx = t + ii*256;
      int row = idx >> 5, gg = idx & 31;
      float4 v = *reinterpret_cast<const float4*>(&lds[0][(row+6)*LCP + 8 + 4*gg]);
      *reinterpret_cast<float4*>(out + (size_t)(r0+row)*WW + c0 + 4*gg) = v;
      float vv[4] = {v.x, v.y, v.z, v.w};
      #pragma unroll
      for (int i = 0; i < 4; i++){
        unsigned key = keyf(vv[i]);
        unsigned hi = key >> 16;
        if (hi >= KEYLO && hi < KEYHI_){
          unsigned bin = hi - KEYLO;
          atomicAdd(&lh[bin >> 1], 1u << ((bin & 1) << 4));
        }
        else if (hi < KEYLO) uc++;
        else                 oc++;
      }
    }

    if (tt == 0){
      __syncthreads();                   // all reads of lds done
      #pragma unroll
      for (int j = 0; j < 7; j++){
        int idx = t + j*256;
        if (idx < LR*36){
          int lr = idx / 36, gq = idx % 36;
          *reinterpret_cast<float4*>(&lds[0][lr*LCP + 4*gq]) = pref[j];
        }
      }
      __syncthreads();
      tile += MORPH_BLOCKS;
    }
  }

  __syncthreads();
  for (int i = threadIdx.x; i < NBINS/2; i += 256){
    unsigned w = lh[i];
    if (w & 0xFFFFu) atomicAdd(&gh[2*i],   w & 0xFFFFu);
    if (w >> 16)     atomicAdd(&gh[2*i+1], w >> 16);
  }
  if (uc) atomicAdd(under, uc);
  if (oc) atomicAdd(over, oc);
}

__global__ void scan_coarse_k(const unsigned* __restrict__ gh, const unsigned* __restrict__ under,
                              Scal* __restrict__ sc){
  __shared__ unsigned part[256];
  __shared__ unsigned excl[256];
  int t = threadIdx.x;
  unsigned loc = 0;
  #pragma unroll
  for (int i = 0; i < NBINS/256; i++) loc += gh[t*(NBINS/256) + i];
  part[t] = loc;
  __syncthreads();
  if (t == 0){
    unsigned run = under[0];
    for (int i = 0; i < 256; i++){ excl[i] = run; run += part[i]; }
  }
  __syncthreads();
  unsigned run = excl[t];
  const unsigned r0 = RANK0, r1 = RANK0 + 1;
  #pragma unroll
  for (int i = 0; i < NBINS/256; i++){
    unsigned idx = t*(NBINS/256) + i;
    unsigned cc = gh[idx];
    if (cc){
      if (r0 >= run && r0 - run < cc){ sc->keyhiA = KEYLO + idx; sc->rA = r0 - run; }
      if (r1 >= run && r1 - run < cc){ sc->keyhiB = KEYLO + idx; sc->rB = r1 - run; }
    }
    run += cc;
  }
}

// mid-byte histogram (bits 15..8) of keys whose hi16 matches keyhiA / keyhiB
__global__ __launch_bounds__(256)
void fine_mid_k(const float* __restrict__ x, const Scal* __restrict__ sc,
                unsigned* __restrict__ midA, unsigned* __restrict__ midB){
  __shared__ unsigned hA[256], hB[256];
  hA[threadIdx.x] = 0; hB[threadIdx.x] = 0;
  __syncthreads();
  unsigned ha = sc->keyhiA, hb = sc->keyhiB;
  bool dup = (ha == hb);
  const int nItems = NN/4;
  for (int it = blockIdx.x*blockDim.x + threadIdx.x; it < nItems; it += gridDim.x*blockDim.x){
    float4 v = reinterpret_cast<const float4*>(x)[it];
    float vv[4] = {v.x, v.y, v.z, v.w};
    #pragma unroll
    for (int t = 0; t < 4; t++){
      unsigned key = keyf(vv[t]);
      unsigned hi = key >> 16;
      if (hi == ha)      atomicAdd(&hA[(key >> 8) & 0xFFu], 1u);
      else if (hi == hb) atomicAdd(&hB[(key >> 8) & 0xFFu], 1u);
    }
  }
  __syncthreads();
  unsigned ca = hA[threadIdx.x];
  if (ca) atomicAdd(&midA[threadIdx.x], ca);
  if (!dup){
    unsigned cb = hB[threadIdx.x];
    if (cb) atomicAdd(&midB[threadIdx.x], cb);
  }
}

__global__ void scan_mid_k(const unsigned* __restrict__ midA, const unsigned* __restrict__ midB,
                           Scal* __restrict__ sc){
  __shared__ unsigned h[256], excl[256];
  int t = threadIdx.x;
  bool dup = (sc->keyhiA == sc->keyhiB);
  unsigned rA = sc->rA, rB = sc->rB;
  h[t] = midA[t];
  __syncthreads();
  if (t == 0){ unsigned run = 0; for (int i = 0; i < 256; i++){ excl[i] = run; run += h[i]; } }
  __syncthreads();
  if (rA >= excl[t] && rA - excl[t] < h[t]){ sc->midA_ = (unsigned)t; sc->rA2 = rA - excl[t]; }
  if (dup && rB >= excl[t] && rB - excl[t] < h[t]){ sc->midB_ = (unsigned)t; sc->rB2 = rB - excl[t]; }
  if (!dup){
    __syncthreads();
    h[t] = midB[t];
    __syncthreads();
    if (t == 0){ unsigned run = 0; for (int i = 0; i < 256; i++){ excl[i] = run; run += h[i]; } }
    __syncthreads();
    if (rB >= excl[t] && rB - excl[t] < h[t]){ sc->midB_ = (unsigned)t; sc->rB2 = rB - excl[t]; }
  }
}

// low-byte histogram of keys with hi16 AND mid byte matching
__global__ __launch_bounds__(256)
void fine_low_k(const float* __restrict__ x, const Scal* __restrict__ sc,
                unsigned* __restrict__ lowA, unsigned* __restrict__ lowB){
  __shared__ unsigned hA[256], hB[256];
  hA[threadIdx.x] = 0; hB[threadIdx.x] = 0;
  __syncthreads();
  unsigned ha = sc->keyhiA, hb = sc->keyhiB;
  unsigned ma = sc->midA_, mb = sc->midB_;
  bool dup = (ha == hb) && (ma == mb);
  const int nItems = NN/4;
  for (int it = blockIdx.x*blockDim.x + threadIdx.x; it < nItems; it += gridDim.x*blockDim.x){
    float4 v = reinterpret_cast<const float4*>(x)[it];
    float vv[4] = {v.x, v.y, v.z, v.w};
    #pragma unroll
    for (int t = 0; t < 4; t++){
      unsigned key = keyf(vv[t]);
      unsigned hi = key >> 16;
      unsigned m  = (key >> 8) & 0xFFu;
      if (hi == ha && m == ma)      atomicAdd(&hA[key & 0xFFu], 1u);
      else if (hi == hb && m == mb) atomicAdd(&hB[key & 0xFFu], 1u);
    }
  }
  __syncthreads();
  unsigned ca = hA[threadIdx.x];
  if (ca) atomicAdd(&lowA[threadIdx.x], ca);
  if (!dup){
    unsigned cb = hB[threadIdx.x];
    if (cb) atomicAdd(&lowB[threadIdx.x], cb);
  }
}

__global__ void scan_low_k(const unsigned* __restrict__ lowA, const unsigned* __restrict__ lowB,
                           Scal* __restrict__ sc){
  __shared__ unsigned h[256], excl[256];
  __shared__ unsigned kfound[2];
  int t = threadIdx.x;
  bool dup = (sc->keyhiA == sc->keyhiB) && (sc->midA_ == sc->midB_);
  unsigned rA2 = sc->rA2, rB2 = sc->rB2;
  h[t] = lowA[t];
  __syncthreads();
  if (t == 0){ unsigned run = 0; for (int i = 0; i < 256; i++){ excl[i] = run; run += h[i]; } }
  __syncthreads();
  if (rA2 >= excl[t] && rA2 - excl[t] < h[t]) kfound[0] = (unsigned)t;
  if (dup && rB2 >= excl[t] && rB2 - excl[t] < h[t]) kfound[1] = (unsigned)t;
  if (!dup){
    __syncthreads();
    h[t] = lowB[t];
    __syncthreads();
    if (t == 0){ unsigned run = 0; for (int i = 0; i < 256; i++){ excl[i] = run; run += h[i]; } }
    __syncthreads();
    if (rB2 >= excl[t] && rB2 - excl[t] < h[t]) kfound[1] = (unsigned)t;
  }
  __syncthreads();
  if (t == 0){
    unsigned ka = (sc->keyhiA << 16) | (sc->midA_ << 8) | kfound[0];
    unsigned kb = (sc->keyhiB << 16) | (sc->midB_ << 8) | kfound[1];
    double va = (double)keyinv(ka), vb = (double)keyinv(kb);
    const double FRAC = 0.4*(double)(NN-1) - (double)RANK0;   // np's interpolation gamma
    sc->thr = va + (vb - va) * FRAC;
  }
}

// 6-col window of global row via 1 float4 + shuffles (scalar patch on lanes 0/63)
__device__ __forceinline__ void growin(const float* __restrict__ p, int row, int q, int lane,
                                       float w[6]){
  if ((unsigned)row >= (unsigned)HH){
    w[0]=w[1]=w[2]=w[3]=w[4]=w[5]=0.f;
    return;
  }
  const float* rp = p + (size_t)row * WW;
  float4 v = *reinterpret_cast<const float4*>(rp + 4*q);
  float L = __shfl_up(v.w, 1);
  float R = __shfl_down(v.x, 1);
  if (q == 0)            L = 0.f;
  else if (lane == 0)    L = rp[4*q - 1];
  if (q == 511)          R = 0.f;
  else if (lane == 63)   R = rp[4*q + 4];
  w[0]=L; w[1]=v.x; w[2]=v.y; w[3]=v.z; w[4]=v.w; w[5]=R;
}

// balloon step: aux = 1 + M9(x) inline; xb = (origin > thr) ? aux : x.
// f64 partial sums of origin, xb, origin*xb per block.
__global__ __launch_bounds__(256)
void balloon_k(const float* __restrict__ x, const float* __restrict__ orig,
               float* __restrict__ xb, const Scal* __restrict__ sc, double* __restrict__ part){
  double thr = sc->thr;
  double s0 = 0.0, s1 = 0.0, s2 = 0.0;   // So, Sx, Sox
  const int nItems = NN/4;
  const int lane = threadIdx.x & 63;
  for (int it = blockIdx.x*blockDim.x + threadIdx.x; it < nItems; it += gridDim.x*blockDim.x){
    int i = it >> 9;
    int q = it & 511;
    float a[6], b[6], c[6];
    growin(x, i-1, q, lane, a);
    growin(x, i,   q, lane, b);
    growin(x, i+1, q, lane, c);
    float4 og = *reinterpret_cast<const float4*>(orig + (size_t)i*WW + 4*q);
    float ov[4] = {og.x, og.y, og.z, og.w};
    float r[4];
    #pragma unroll
    for (int t = 0; t < 4; t++){
      float M9 = mx3(mx3(a[t],a[t+1],a[t+2]), mx3(b[t],b[t+1],b[t+2]), mx3(c[t],c[t+1],c[t+2]));
      float aux = 1.0f + M9;
      float nx = ((double)ov[t] > thr) ? aux : b[t+1];
      r[t] = nx;
      s0 += (double)ov[t];
      s1 += (double)nx;
      s2 += (double)ov[t] * (double)nx;
    }
    *reinterpret_cast<float4*>(xb + (size_t)i*WW + 4*q) = make_float4(r[0],r[1],r[2],r[3]);
  }
  for (int off = 32; off > 0; off >>= 1){
    s0 += __shfl_down(s0, off);
    s1 += __shfl_down(s1, off);
    s2 += __shfl_down(s2, off);
  }
  __shared__ double red[4][3];
  int wv = threadIdx.x >> 6;
  if (lane == 0){ red[wv][0] = s0; red[wv][1] = s1; red[wv][2] = s2; }
  __syncthreads();
  if (threadIdx.x == 0){
    part[blockIdx.x*3+0] = red[0][0]+red[1][0]+red[2][0]+red[3][0];
    part[blockIdx.x*3+1] = red[0][1]+red[1][1]+red[2][1]+red[3][1];
    part[blockIdx.x*3+2] = red[0][2]+red[1][2]+red[2][2]+red[3][2];
  }
}

__global__ void c0c1_k(const double* __restrict__ part, Scal* __restrict__ sc){
  int t = threadIdx.x;
  double s0 = 0, s1 = 0, s2 = 0;
  for (int b = t; b < NPART; b += 256){
    s0 += part[b*3+0]; s1 += part[b*3+1]; s2 += part[b*3+2];
  }
  for (int off = 32; off > 0; off >>= 1){
    s0 += __shfl_down(s0, off);
    s1 += __shfl_down(s1, off);
    s2 += __shfl_down(s2, off);
  }
  __shared__ double red[4][3];
  int lane = t & 63, wv = t >> 6;
  if (lane == 0){ red[wv][0] = s0; red[wv][1] = s1; red[wv][2] = s2; }
  __syncthreads();
  if (t == 0){
    double So = red[0][0]+red[1][0]+red[2][0]+red[3][0];
    double Sx = red[0][1]+red[1][1]+red[2][1]+red[3][1];
    double Sox= red[0][2]+red[1][2]+red[2][2]+red[3][2];
    sc->c0 = (So - Sox) / ((double)NN - Sx + 1e-8);
    sc->c1 = Sox / (Sx + 1e-8);
  }
}

__global__ __launch_bounds__(256)
void final_k(const float* __restrict__ orig, const float* __restrict__ xb,
             const Scal* __restrict__ sc, float* __restrict__ out){
  double c0 = sc->c0, c1 = sc->c1;
  const int nItems = NN/4;
  for (int it = blockIdx.x*blockDim.x + threadIdx.x; it < nItems; it += gridDim.x*blockDim.x){
    float4 og = reinterpret_cast<const float4*>(orig)[it];
    float4 xv = reinterpret_cast<const float4*>(xb)[it];
    float ov[4] = {og.x, og.y, og.z, og.w};
    float xx[4] = {xv.x, xv.y, xv.z, xv.w};
    float r[4];
    #pragma unroll
    for (int t = 0; t < 4; t++){
      double o = (double)ov[t];
      double d1 = o - c1, d0 = o - c0;
      double cv = d1*d1 - d0*d0;
      r[t] = (cv < 0.0) ? 1.0f : ((cv > 0.0) ? 0.0f : xx[t]);
    }
    reinterpret_cast<float4*>(out)[it] = make_float4(r[0],r[1],r[2],r[3]);
  }
}

extern "C" void kernel_launch(void* const* d_in, const int* in_sizes, int n_in,
                              void* d_out, int out_size, void* d_ws, size_t ws_size,
                              hipStream_t stream) {
  const float* input  = (const float*)d_in[0];
  const float* origin = (const float*)d_in[1];
  float* out = (float*)d_out;

  char* ws = (char*)d_ws;
  float*    bufA   = (float*)ws;
  unsigned* coarse = (unsigned*)(ws + OFF_COARSE);
  unsigned* under  = (unsigned*)(ws + OFF_UNDER);
  unsigned* over   = (unsigned*)(ws + OFF_OVER);
  unsigned* midA   = (unsigned*)(ws + OFF_MIDA);
  unsigned* midB   = (unsigned*)(ws + OFF_MIDB);
  unsigned* lowA   = (unsigned*)(ws + OFF_LOWA);
  unsigned* lowB   = (unsigned*)(ws + OFF_LOWB);
  Scal*     scal   = (Scal*)(ws + OFF_SCAL);
  double*   part   = (double*)(ws + OFF_PART);

  hipMemsetAsync(ws + OFF_CTL, 0, CTL_BYTES, stream);

  // all 6 smoothing ops + coarse hist; 2 tiles/block with register prefetch
  fused_morph_k<<<MORPH_BLOCKS, 256, 0, stream>>>(input, out, coarse, under, over);

  scan_coarse_k<<<1, 256, 0, stream>>>(coarse, under, scal);
  fine_mid_k<<<2048, 256, 0, stream>>>(out, scal, midA, midB);
  scan_mid_k<<<1, 256, 0, stream>>>(midA, midB, scal);
  fine_low_k<<<2048, 256, 0, stream>>>(out, scal, lowA, lowB);
  scan_low_k<<<1, 256, 0, stream>>>(lowA, lowB, scal);

  balloon_k<<<NPART, 256, 0, stream>>>(out, origin, bufA, scal, part);   // xb in bufA
  c0c1_k<<<1, 256, 0, stream>>>(part, scal);
  final_k<<<2048, 256, 0, stream>>>(origin, bufA, scal, out);
}